// Round 1
// baseline (607.254 us; speedup 1.0000x reference)
//
#include <hip/hip_runtime.h>
#include <hip/hip_bf16.h>

#define DEV __device__ __forceinline__

typedef __attribute__((ext_vector_type(8))) short short8;
typedef __attribute__((ext_vector_type(4))) float f32x4;
typedef unsigned short u16;
typedef unsigned int u32;

// B=4, T=2048, D=1024, H=16, E=64, M = B*T = 8192

DEV u16 f2bf(float f) {
    union { __hip_bfloat16 h; u16 u; } cv;
    cv.h = __float2bfloat16(f);
    return cv.u;
}

DEV void gload_lds16(const void* g, void* l) {
    __builtin_amdgcn_global_load_lds((const __attribute__((address_space(1))) u32*)g,
                                     (__attribute__((address_space(3))) u32*)l, 16, 0, 0);
}

// ---------- transpose fp32 -> bf16 : out[c][r] = in[r][c] per blockIdx.z slab ----------
__global__ __launch_bounds__(256) void k_transpose_f32_bf16(const float* __restrict__ in,
                                                            u16* __restrict__ out,
                                                            int R, int C) {
    __shared__ float tile[64][65];
    const int x = threadIdx.x & 63, y = threadIdx.x >> 6;
    const long slab = (long)blockIdx.z * R * C;
    const int r0 = blockIdx.x * 64, c0 = blockIdx.y * 64;
#pragma unroll
    for (int i = 0; i < 16; ++i) {
        int rr = y + 4 * i;
        tile[rr][x] = in[slab + (long)(r0 + rr) * C + (c0 + x)];
    }
    __syncthreads();
#pragma unroll
    for (int i = 0; i < 16; ++i) {
        int cc = y + 4 * i;
        out[slab + (long)(c0 + cc) * R + (r0 + x)] = f2bf(tile[x][cc]);
    }
}

// ---------- transpose bf16 -> bf16 ----------
__global__ __launch_bounds__(256) void k_transpose_bf16(const u16* __restrict__ in,
                                                        u16* __restrict__ out,
                                                        int R, int C) {
    __shared__ u16 tile[64][65];
    const int x = threadIdx.x & 63, y = threadIdx.x >> 6;
    const long slab = (long)blockIdx.z * R * C;
    const int r0 = blockIdx.x * 64, c0 = blockIdx.y * 64;
#pragma unroll
    for (int i = 0; i < 16; ++i) {
        int rr = y + 4 * i;
        tile[rr][x] = in[slab + (long)(r0 + rr) * C + (c0 + x)];
    }
    __syncthreads();
#pragma unroll
    for (int i = 0; i < 16; ++i) {
        int cc = y + 4 * i;
        out[slab + (long)(c0 + cc) * R + (r0 + x)] = tile[x][cc];
    }
}

// ---------- GEMM: M=8192, N=1024, K=1024, BM=BN=128, BK=32 ----------
// MODE 0: A = fp32 [8192][1024] (cast to bf16 in staging); C -> bf16 [b][h][t][e]
// MODE 1: A = bf16 attn [b][h][t][e] gathered;             C -> fp32 [8192][1024]
template<int MODE>
__global__ __launch_bounds__(256) void k_gemm(const void* __restrict__ Aptr,
                                              const u16* __restrict__ Bt,   // [N=1024][K=1024] bf16
                                              void* __restrict__ Cptr) {
    __shared__ u16 As[128 * 32];
    __shared__ u16 Bs[128 * 32];
    const int tid = threadIdx.x;
    const int lane = tid & 63, wave = tid >> 6;
    const int l15 = lane & 15, l4 = lane >> 4;
    const int wr = wave >> 1, wc = wave & 1;
    const int brow = blockIdx.x * 128, bcol = blockIdx.y * 128;

    f32x4 acc[4][4] = {};

    for (int k0 = 0; k0 < 1024; k0 += 32) {
        __syncthreads();   // protect LDS WAR from previous iteration's reads
        // stage B via async global->LDS (16B per lane)
#pragma unroll
        for (int cc = 0; cc < 2; ++cc) {
            const int c = tid + cc * 256;
            const u16* src = Bt + (long)(bcol + (c >> 2)) * 1024 + k0 + (c & 3) * 8;
            gload_lds16(src, &Bs[cc * 2048 + wave * 512]);
        }
        if (MODE == 0) {
            const float* Af = (const float*)Aptr;
#pragma unroll
            for (int cc = 0; cc < 2; ++cc) {
                const int c = tid + cc * 256;
                const float* src = Af + (long)(brow + (c >> 2)) * 1024 + k0 + (c & 3) * 8;
                float4 v0 = *(const float4*)src;
                float4 v1 = *(const float4*)(src + 4);
                short8 pk;
                pk[0] = (short)f2bf(v0.x); pk[1] = (short)f2bf(v0.y);
                pk[2] = (short)f2bf(v0.z); pk[3] = (short)f2bf(v0.w);
                pk[4] = (short)f2bf(v1.x); pk[5] = (short)f2bf(v1.y);
                pk[6] = (short)f2bf(v1.z); pk[7] = (short)f2bf(v1.w);
                *(short8*)&As[c * 8] = pk;
            }
        } else {
            const u16* Ab = (const u16*)Aptr;
            const int h = k0 >> 6, ek = k0 & 63;
#pragma unroll
            for (int cc = 0; cc < 2; ++cc) {
                const int c = tid + cc * 256;
                const int g = brow + (c >> 2);
                const int b = g >> 11, t = g & 2047;
                const u16* src = Ab + (long)(b * 16 + h) * 131072 + (long)t * 64 + ek + (c & 3) * 8;
                gload_lds16(src, &As[cc * 2048 + wave * 512]);
            }
        }
        __syncthreads();   // drains vmcnt+lgkmcnt

        short8 af[4], bfr[4];
#pragma unroll
        for (int m = 0; m < 4; ++m)
            af[m] = *(const short8*)&As[(wr * 64 + m * 16 + l15) * 32 + l4 * 8];
#pragma unroll
        for (int n = 0; n < 4; ++n)
            bfr[n] = *(const short8*)&Bs[(wc * 64 + n * 16 + l15) * 32 + l4 * 8];
#pragma unroll
        for (int m = 0; m < 4; ++m)
#pragma unroll
            for (int n = 0; n < 4; ++n)
                acc[m][n] = __builtin_amdgcn_mfma_f32_16x16x32_bf16(af[m], bfr[n], acc[m][n], 0, 0, 0);
    }

    // epilogue: D lane layout: row=(lane>>4)*4+r, col=lane&15
#pragma unroll
    for (int m = 0; m < 4; ++m) {
#pragma unroll
        for (int n = 0; n < 4; ++n) {
#pragma unroll
            for (int r = 0; r < 4; ++r) {
                const int g = brow + wr * 64 + m * 16 + l4 * 4 + r;
                const int ng = bcol + wc * 64 + n * 16 + l15;
                if (MODE == 0) {
                    const int b = g >> 11, t = g & 2047;
                    const int h = ng >> 6, e = ng & 63;
                    ((u16*)Cptr)[(long)(b * 16 + h) * 131072 + (long)t * 64 + e] = f2bf(acc[m][n][r]);
                } else {
                    ((float*)Cptr)[(long)g * 1024 + ng] = acc[m][n][r];
                }
            }
        }
    }
}

// ---------- flash attention ----------
// grid: 64 (b,h) * 32 q-tiles; block 256 = 4 waves; wave handles 16 q-rows.
// Qh,Kh: [bh][2048][64] bf16 ; VhT: [bh][64][2048] bf16 ; attn out: [bh][2048][64] bf16
__global__ __launch_bounds__(256) void k_flash(const u16* __restrict__ Qh,
                                               const u16* __restrict__ Kh,
                                               const u16* __restrict__ VhT,
                                               u16* __restrict__ attn) {
    __shared__ u16 P[4][16 * 72];   // per-wave P tile, stride 72 (144B, 16B-aligned rows)
    const int tid = threadIdx.x, lane = tid & 63, w = tid >> 6;
    const int l15 = lane & 15, l4 = lane >> 4;
    const int bh = blockIdx.x >> 5, qt = blockIdx.x & 31;
    const long base = (long)bh * (2048 * 64);
    const int q0 = qt * 64 + w * 16;

    short8 aq0 = *(const short8*)(Qh + base + (long)(q0 + l15) * 64 + l4 * 8);
    short8 aq1 = *(const short8*)(Qh + base + (long)(q0 + l15) * 64 + 32 + l4 * 8);

    float mrow[4], lrow[4];
    f32x4 oacc[4] = {};
#pragma unroll
    for (int r = 0; r < 4; ++r) { mrow[r] = -INFINITY; lrow[r] = 0.f; }

    u16* Pw = &P[w][0];

    for (int kv0 = 0; kv0 < 2048; kv0 += 64) {
        float pv[4][4];   // [nt][r]: S at kv = nt*16 + l15, q = l4*4 + r
        // QK^T: S[16q][64kv], A/B frags straight from global (row-major [t][64] matches)
#pragma unroll
        for (int nt = 0; nt < 4; ++nt) {
            const u16* kp = Kh + base + (long)(kv0 + nt * 16 + l15) * 64 + l4 * 8;
            short8 bk0 = *(const short8*)kp;
            short8 bk1 = *(const short8*)(kp + 32);
            f32x4 z = {};
            z = __builtin_amdgcn_mfma_f32_16x16x32_bf16(aq0, bk0, z, 0, 0, 0);
            z = __builtin_amdgcn_mfma_f32_16x16x32_bf16(aq1, bk1, z, 0, 0, 0);
#pragma unroll
            for (int r = 0; r < 4; ++r) pv[nt][r] = z[r] * 0.125f;
        }
        // online softmax (row reduction across the 16-lane group: masks 1,2,4,8)
#pragma unroll
        for (int r = 0; r < 4; ++r) {
            float v = fmaxf(fmaxf(pv[0][r], pv[1][r]), fmaxf(pv[2][r], pv[3][r]));
#pragma unroll
            for (int mk = 1; mk < 16; mk <<= 1) v = fmaxf(v, __shfl_xor(v, mk, 64));
            const float nm = fmaxf(mrow[r], v);
            const float sc = __expf(mrow[r] - nm);
            mrow[r] = nm;
            float rs = 0.f;
#pragma unroll
            for (int nt = 0; nt < 4; ++nt) { float p = __expf(pv[nt][r] - nm); pv[nt][r] = p; rs += p; }
#pragma unroll
            for (int mk = 1; mk < 16; mk <<= 1) rs += __shfl_xor(rs, mk, 64);
            lrow[r] = lrow[r] * sc + rs;
#pragma unroll
            for (int et = 0; et < 4; ++et) oacc[et][r] *= sc;
        }
        // P -> LDS (wave-local transpose to MFMA A layout)
#pragma unroll
        for (int r = 0; r < 4; ++r)
#pragma unroll
            for (int nt = 0; nt < 4; ++nt)
                Pw[(l4 * 4 + r) * 72 + nt * 16 + l15] = f2bf(pv[nt][r]);
        __threadfence_block();
        // PV: O[16q][64e] += P[16,64] * V[64,64]
#pragma unroll
        for (int ks = 0; ks < 2; ++ks) {
            short8 ap = *(const short8*)(Pw + l15 * 72 + ks * 32 + l4 * 8);
#pragma unroll
            for (int et = 0; et < 4; ++et) {
                const u16* vp = VhT + base + (long)(et * 16 + l15) * 2048 + kv0 + ks * 32 + l4 * 8;
                short8 bv = *(const short8*)vp;
                oacc[et] = __builtin_amdgcn_mfma_f32_16x16x32_bf16(ap, bv, oacc[et], 0, 0, 0);
            }
        }
        __threadfence_block();
    }
#pragma unroll
    for (int et = 0; et < 4; ++et) {
#pragma unroll
        for (int r = 0; r < 4; ++r) {
            const int q = q0 + l4 * 4 + r;
            attn[base + (long)q * 64 + et * 16 + l15] = f2bf(oacc[et][r] / lrow[r]);
        }
    }
}

extern "C" void kernel_launch(void* const* d_in, const int* in_sizes, int n_in,
                              void* d_out, int out_size, void* d_ws, size_t ws_size,
                              hipStream_t stream) {
    (void)in_sizes; (void)n_in; (void)out_size; (void)ws_size;
    const float* Q  = (const float*)d_in[0];
    const float* K  = (const float*)d_in[1];
    const float* V  = (const float*)d_in[2];
    const float* Wq = (const float*)d_in[3];
    const float* Wk = (const float*)d_in[4];
    const float* Wv = (const float*)d_in[5];
    const float* Wo = (const float*)d_in[6];

    char* ws = (char*)d_ws;
    auto WS = [&](size_t mb) { return (u16*)(ws + (mb << 20)); };
    u16* WqT  = WS(0);    // [1024][1024] bf16 (B^T for Q proj)   2MB
    u16* WkT  = WS(2);
    u16* WvT  = WS(4);
    u16* WoT  = WS(6);
    u16* Qh   = WS(8);    // [64][2048][64] bf16   16MB
    u16* Kh   = WS(24);
    u16* Vh   = WS(40);
    u16* VhT  = WS(56);   // [64][64][2048]
    u16* attn = WS(72);   // [64][2048][64]        ends at 88MB

    dim3 b256(256);
    // weights -> B^T bf16 layouts. Wq/Wk/Wv: per head [1024d][64e] -> [64e][1024d]
    k_transpose_f32_bf16<<<dim3(16, 1, 16), b256, 0, stream>>>(Wq, WqT, 1024, 64);
    k_transpose_f32_bf16<<<dim3(16, 1, 16), b256, 0, stream>>>(Wk, WkT, 1024, 64);
    k_transpose_f32_bf16<<<dim3(16, 1, 16), b256, 0, stream>>>(Wv, WvT, 1024, 64);
    // Wo: [1024 he][1024 D] -> [1024 D][1024 he]
    k_transpose_f32_bf16<<<dim3(16, 16, 1), b256, 0, stream>>>(Wo, WoT, 1024, 1024);

    // projections
    k_gemm<0><<<dim3(64, 8), b256, 0, stream>>>(Q, WqT, Qh);
    k_gemm<0><<<dim3(64, 8), b256, 0, stream>>>(K, WkT, Kh);
    k_gemm<0><<<dim3(64, 8), b256, 0, stream>>>(V, WvT, Vh);

    // V transpose per (b,h): [2048][64] -> [64][2048]
    k_transpose_bf16<<<dim3(32, 1, 64), b256, 0, stream>>>(Vh, VhT, 2048, 64);

    // attention
    k_flash<<<dim3(2048), b256, 0, stream>>>(Qh, Kh, VhT, attn);

    // output projection
    k_gemm<1><<<dim3(64, 8), b256, 0, stream>>>(attn, WoT, (float*)d_out);
}

// Round 2
// 280.128 us; speedup vs baseline: 2.1678x; 2.1678x over previous
//
#include <hip/hip_runtime.h>
#include <hip/hip_bf16.h>

#define DEV __device__ __forceinline__

typedef __attribute__((ext_vector_type(8))) short short8;
typedef __attribute__((ext_vector_type(4))) float f32x4;
typedef unsigned short u16;
typedef unsigned int u32;

// B=4, T=2048, D=1024, H=16, E=64, M = B*T = 8192

DEV u16 f2bf(float f) {
    union { __hip_bfloat16 h; u16 u; } cv;
    cv.h = __float2bfloat16(f);
    return cv.u;
}

DEV void gload_lds16(const void* g, void* l) {
    __builtin_amdgcn_global_load_lds((const __attribute__((address_space(1))) u32*)g,
                                     (__attribute__((address_space(3))) u32*)l, 16, 0, 0);
}

// ---------- transpose fp32 -> bf16 : out[c][r] = in[r][c] per blockIdx.z slab ----------
__global__ __launch_bounds__(256) void k_transpose_f32_bf16(const float* __restrict__ in,
                                                            u16* __restrict__ out,
                                                            int R, int C) {
    __shared__ float tile[64][65];
    const int x = threadIdx.x & 63, y = threadIdx.x >> 6;
    const long slab = (long)blockIdx.z * R * C;
    const int r0 = blockIdx.x * 64, c0 = blockIdx.y * 64;
#pragma unroll
    for (int i = 0; i < 16; ++i) {
        int rr = y + 4 * i;
        tile[rr][x] = in[slab + (long)(r0 + rr) * C + (c0 + x)];
    }
    __syncthreads();
#pragma unroll
    for (int i = 0; i < 16; ++i) {
        int cc = y + 4 * i;
        out[slab + (long)(c0 + cc) * R + (r0 + x)] = f2bf(tile[x][cc]);
    }
}

// ---------- transpose bf16 -> bf16 ----------
__global__ __launch_bounds__(256) void k_transpose_bf16(const u16* __restrict__ in,
                                                        u16* __restrict__ out,
                                                        int R, int C) {
    __shared__ u16 tile[64][65];
    const int x = threadIdx.x & 63, y = threadIdx.x >> 6;
    const long slab = (long)blockIdx.z * R * C;
    const int r0 = blockIdx.x * 64, c0 = blockIdx.y * 64;
#pragma unroll
    for (int i = 0; i < 16; ++i) {
        int rr = y + 4 * i;
        tile[rr][x] = in[slab + (long)(r0 + rr) * C + (c0 + x)];
    }
    __syncthreads();
#pragma unroll
    for (int i = 0; i < 16; ++i) {
        int cc = y + 4 * i;
        out[slab + (long)(c0 + cc) * R + (r0 + x)] = tile[x][cc];
    }
}

// ---------- GEMM: M=8192, N=1024, K=1024, BM=BN=128, BK=32 ----------
// MODE 0: A = fp32 [8192][1024] (cast to bf16 in staging); C -> bf16 [b][h][t][e]
// MODE 1: A = bf16 attn [b][h][t][e] gathered;             C -> fp32 [8192][1024]
template<int MODE>
__global__ __launch_bounds__(256) void k_gemm(const void* __restrict__ Aptr,
                                              const u16* __restrict__ Bt,   // [N=1024][K=1024] bf16
                                              void* __restrict__ Cptr) {
    __shared__ u16 As[128 * 32];
    __shared__ u16 Bs[128 * 32];
    const int tid = threadIdx.x;
    const int lane = tid & 63, wave = tid >> 6;
    const int l15 = lane & 15, l4 = lane >> 4;
    const int wr = wave >> 1, wc = wave & 1;
    const int brow = blockIdx.x * 128, bcol = blockIdx.y * 128;

    f32x4 acc[4][4] = {};

    for (int k0 = 0; k0 < 1024; k0 += 32) {
        __syncthreads();   // protect LDS WAR from previous iteration's reads
        // stage B via async global->LDS (16B per lane)
#pragma unroll
        for (int cc = 0; cc < 2; ++cc) {
            const int c = tid + cc * 256;
            const u16* src = Bt + (long)(bcol + (c >> 2)) * 1024 + k0 + (c & 3) * 8;
            gload_lds16(src, &Bs[cc * 2048 + wave * 512]);
        }
        if (MODE == 0) {
            const float* Af = (const float*)Aptr;
#pragma unroll
            for (int cc = 0; cc < 2; ++cc) {
                const int c = tid + cc * 256;
                const float* src = Af + (long)(brow + (c >> 2)) * 1024 + k0 + (c & 3) * 8;
                float4 v0 = *(const float4*)src;
                float4 v1 = *(const float4*)(src + 4);
                short8 pk;
                pk[0] = (short)f2bf(v0.x); pk[1] = (short)f2bf(v0.y);
                pk[2] = (short)f2bf(v0.z); pk[3] = (short)f2bf(v0.w);
                pk[4] = (short)f2bf(v1.x); pk[5] = (short)f2bf(v1.y);
                pk[6] = (short)f2bf(v1.z); pk[7] = (short)f2bf(v1.w);
                *(short8*)&As[c * 8] = pk;
            }
        } else {
            const u16* Ab = (const u16*)Aptr;
            const int h = k0 >> 6, ek = k0 & 63;
#pragma unroll
            for (int cc = 0; cc < 2; ++cc) {
                const int c = tid + cc * 256;
                const int g = brow + (c >> 2);
                const int b = g >> 11, t = g & 2047;
                const u16* src = Ab + (long)(b * 16 + h) * 131072 + (long)t * 64 + ek + (c & 3) * 8;
                gload_lds16(src, &As[cc * 2048 + wave * 512]);
            }
        }
        __syncthreads();   // drains vmcnt+lgkmcnt

        short8 af[4], bfr[4];
#pragma unroll
        for (int m = 0; m < 4; ++m)
            af[m] = *(const short8*)&As[(wr * 64 + m * 16 + l15) * 32 + l4 * 8];
#pragma unroll
        for (int n = 0; n < 4; ++n)
            bfr[n] = *(const short8*)&Bs[(wc * 64 + n * 16 + l15) * 32 + l4 * 8];
#pragma unroll
        for (int m = 0; m < 4; ++m)
#pragma unroll
            for (int n = 0; n < 4; ++n)
                acc[m][n] = __builtin_amdgcn_mfma_f32_16x16x32_bf16(af[m], bfr[n], acc[m][n], 0, 0, 0);
    }

    // epilogue: D lane layout: row=(lane>>4)*4+r, col=lane&15
#pragma unroll
    for (int m = 0; m < 4; ++m) {
#pragma unroll
        for (int n = 0; n < 4; ++n) {
#pragma unroll
            for (int r = 0; r < 4; ++r) {
                const int g = brow + wr * 64 + m * 16 + l4 * 4 + r;
                const int ng = bcol + wc * 64 + n * 16 + l15;
                if (MODE == 0) {
                    const int b = g >> 11, t = g & 2047;
                    const int h = ng >> 6, e = ng & 63;
                    ((u16*)Cptr)[(long)(b * 16 + h) * 131072 + (long)t * 64 + e] = f2bf(acc[m][n][r]);
                } else {
                    ((float*)Cptr)[(long)g * 1024 + ng] = acc[m][n][r];
                }
            }
        }
    }
}

// ---------- flash attention v2 ----------
// grid: 1024 blocks = 64 bh * 16 q-tiles (XCD-swizzled); block 256 = 4 waves;
// wave computes 32 q rows (2 groups of 16). KV tiles of 64, K/V staged in LDS
// (double-buffered, XOR-swizzled via pre-swizzled global source).
// Swapped MFMAs: S^T = mfma(K, Q)  -> lane owns q = lane&15 (in-reg softmax)
//                O^T = mfma(V^T, P) -> rescale/epilogue lane-local in q.
__global__ __launch_bounds__(256, 4) void k_flash2(const u16* __restrict__ Qh,
                                                   const u16* __restrict__ Kh,
                                                   const u16* __restrict__ VhT,
                                                   u16* __restrict__ attn) {
    __shared__ u16 Ks[2][64 * 64];   // [kv][d], rows XOR-swizzled in 16B chunks
    __shared__ u16 Vs[2][64 * 64];   // [e][kv], same swizzle
    __shared__ u16 Ps[4][16 * 64];   // per-wave P[q][kv], same swizzle

    const int tid = threadIdx.x, lane = tid & 63, w = tid >> 6;
    const int l15 = lane & 15, l4 = lane >> 4;
    const int wid = blockIdx.x;
    const int swz = (wid & 7) * 128 + (wid >> 3);   // bijective: 1024 % 8 == 0
    const int bh = swz >> 4, qt = swz & 15;
    const long base = (long)bh * (2048 * 64);
    const int q0 = qt * 128 + w * 32;

    // Q fragments: [group][k-half]; B-frag = Q[q=l15-row][k = half*32 + l4*8 ..]
    short8 aq[2][2];
#pragma unroll
    for (int g = 0; g < 2; ++g)
#pragma unroll
        for (int h = 0; h < 2; ++h)
            aq[g][h] = *(const short8*)(Qh + base + (long)(q0 + g * 16 + l15) * 64 + h * 32 + l4 * 8);

    float mrow[2] = {-INFINITY, -INFINITY}, lrow[2] = {0.f, 0.f};
    f32x4 oacc[2][4] = {};

    u16* Pw = &Ps[w][0];

    // staging constants: chunk c covers LDS bytes [c*16, c*16+16); row=c>>3, col16=c&7.
    // source col pre-swizzled so that swizzled ds_reads see K[row][col].
    const int c0 = tid, c1 = tid + 256;
    const int r0 = c0 >> 3, s0 = (c0 & 7) ^ (r0 & 7);
    const int r1 = c1 >> 3, s1 = (c1 & 7) ^ (r1 & 7);

#define STAGE(buf, t) do {                                                        \
    const int kv0_ = (t) * 64;                                                    \
    gload_lds16(Kh + base + (long)(kv0_ + r0) * 64 + s0 * 8, &Ks[buf][w * 512]);  \
    gload_lds16(Kh + base + (long)(kv0_ + r1) * 64 + s1 * 8, &Ks[buf][2048 + w * 512]); \
    gload_lds16(VhT + base + (long)r0 * 2048 + kv0_ + s0 * 8, &Vs[buf][w * 512]); \
    gload_lds16(VhT + base + (long)r1 * 2048 + kv0_ + s1 * 8, &Vs[buf][2048 + w * 512]); \
  } while (0)

    STAGE(0, 0);

    for (int t = 0; t < 32; ++t) {
        const int buf = t & 1;
        __syncthreads();              // drains vmcnt: staged tile t ready; WAR-safe
        if (t < 31) STAGE(buf ^ 1, t + 1);

        const u16* Kb = &Ks[buf][0];
        const u16* Vb = &Vs[buf][0];

#pragma unroll
        for (int g = 0; g < 2; ++g) {
            // ---- QK^T (swapped): S^T[kv][q], lane: q=l15, kv = nt*16 + l4*4 + r
            float pv[4][4];
#pragma unroll
            for (int nt = 0; nt < 4; ++nt) {
                const int row = nt * 16 + l15;
                f32x4 z = {};
#pragma unroll
                for (int ks = 0; ks < 2; ++ks) {
                    short8 kf = *(const short8*)(Kb + row * 64 + (((ks * 4 + l4) ^ (row & 7)) << 3));
                    z = __builtin_amdgcn_mfma_f32_16x16x32_bf16(kf, aq[g][ks], z, 0, 0, 0);
                }
#pragma unroll
                for (int r = 0; r < 4; ++r) pv[nt][r] = z[r] * 0.125f;
            }
            // ---- online softmax: in-register row reduce + 2 shuffles
            float vmax = pv[0][0];
#pragma unroll
            for (int nt = 0; nt < 4; ++nt)
#pragma unroll
                for (int r = 0; r < 4; ++r) vmax = fmaxf(vmax, pv[nt][r]);
            vmax = fmaxf(vmax, __shfl_xor(vmax, 16, 64));
            vmax = fmaxf(vmax, __shfl_xor(vmax, 32, 64));
            const float nm = fmaxf(mrow[g], vmax);
            const float sc = __expf(mrow[g] - nm);
            mrow[g] = nm;
            float rs = 0.f;
#pragma unroll
            for (int nt = 0; nt < 4; ++nt)
#pragma unroll
                for (int pr = 0; pr < 2; ++pr) {
                    float p0 = __expf(pv[nt][pr * 2] - nm);
                    float p1 = __expf(pv[nt][pr * 2 + 1] - nm);
                    rs += p0 + p1;
                    u32 pk = (u32)f2bf(p0) | ((u32)f2bf(p1) << 16);
                    // P[q=l15][kv = nt*16 + l4*4 + pr*2 + {0,1}], swizzled
                    *(u32*)((char*)Pw + l15 * 128 + ((nt * 32 + l4 * 8 + pr * 4) ^ ((l15 & 7) << 4))) = pk;
                }
            rs += __shfl_xor(rs, 16, 64);
            rs += __shfl_xor(rs, 32, 64);
            lrow[g] = lrow[g] * sc + rs;
#pragma unroll
            for (int et = 0; et < 4; ++et)
#pragma unroll
                for (int r = 0; r < 4; ++r) oacc[g][et][r] *= sc;

            asm volatile("s_waitcnt lgkmcnt(0)" ::: "memory");   // P writes visible (same wave)

            // ---- PV (swapped): O^T[e][q] += V^T[e][kv] * P^T[kv][q]
#pragma unroll
            for (int ks = 0; ks < 2; ++ks) {
                short8 pb = *(const short8*)((char*)Pw + l15 * 128 + (((ks * 4 + l4) << 4) ^ ((l15 & 7) << 4)));
#pragma unroll
                for (int et = 0; et < 4; ++et) {
                    const int vrow = et * 16 + l15;
                    short8 vf = *(const short8*)(Vb + vrow * 64 + (((ks * 4 + l4) ^ (vrow & 7)) << 3));
                    oacc[g][et] = __builtin_amdgcn_mfma_f32_16x16x32_bf16(vf, pb, oacc[g][et], 0, 0, 0);
                }
            }
        }
    }
#undef STAGE

    // epilogue: O^T layout: e = et*16 + l4*4 + r, q = l15 (lane-local l)
#pragma unroll
    for (int g = 0; g < 2; ++g) {
        const float inv = 1.0f / lrow[g];
#pragma unroll
        for (int et = 0; et < 4; ++et)
#pragma unroll
            for (int r = 0; r < 4; ++r)
                attn[base + (long)(q0 + g * 16 + l15) * 64 + et * 16 + l4 * 4 + r] =
                    f2bf(oacc[g][et][r] * inv);
    }
}

extern "C" void kernel_launch(void* const* d_in, const int* in_sizes, int n_in,
                              void* d_out, int out_size, void* d_ws, size_t ws_size,
                              hipStream_t stream) {
    (void)in_sizes; (void)n_in; (void)out_size; (void)ws_size;
    const float* Q  = (const float*)d_in[0];
    const float* K  = (const float*)d_in[1];
    const float* V  = (const float*)d_in[2];
    const float* Wq = (const float*)d_in[3];
    const float* Wk = (const float*)d_in[4];
    const float* Wv = (const float*)d_in[5];
    const float* Wo = (const float*)d_in[6];

    char* ws = (char*)d_ws;
    auto WS = [&](size_t mb) { return (u16*)(ws + (mb << 20)); };
    u16* WqT  = WS(0);    // [1024][1024] bf16 (B^T for Q proj)   2MB
    u16* WkT  = WS(2);
    u16* WvT  = WS(4);
    u16* WoT  = WS(6);
    u16* Qh   = WS(8);    // [64][2048][64] bf16   16MB
    u16* Kh   = WS(24);
    u16* Vh   = WS(40);
    u16* VhT  = WS(56);   // [64][64][2048]
    u16* attn = WS(72);   // [64][2048][64]        ends at 88MB

    dim3 b256(256);
    // weights -> B^T bf16 layouts. Wq/Wk/Wv: per head [1024d][64e] -> [64e][1024d]
    k_transpose_f32_bf16<<<dim3(16, 1, 16), b256, 0, stream>>>(Wq, WqT, 1024, 64);
    k_transpose_f32_bf16<<<dim3(16, 1, 16), b256, 0, stream>>>(Wk, WkT, 1024, 64);
    k_transpose_f32_bf16<<<dim3(16, 1, 16), b256, 0, stream>>>(Wv, WvT, 1024, 64);
    // Wo: [1024 he][1024 D] -> [1024 D][1024 he]
    k_transpose_f32_bf16<<<dim3(16, 16, 1), b256, 0, stream>>>(Wo, WoT, 1024, 1024);

    // projections
    k_gemm<0><<<dim3(64, 8), b256, 0, stream>>>(Q, WqT, Qh);
    k_gemm<0><<<dim3(64, 8), b256, 0, stream>>>(K, WkT, Kh);
    k_gemm<0><<<dim3(64, 8), b256, 0, stream>>>(V, WvT, Vh);

    // V transpose per (b,h): [2048][64] -> [64][2048]
    k_transpose_bf16<<<dim3(32, 1, 64), b256, 0, stream>>>(Vh, VhT, 2048, 64);

    // attention
    k_flash2<<<dim3(1024), b256, 0, stream>>>(Qh, Kh, VhT, attn);

    // output projection
    k_gemm<1><<<dim3(64, 8), b256, 0, stream>>>(attn, WoT, (float*)d_out);
}

// Round 3
// 246.010 us; speedup vs baseline: 2.4684x; 1.1387x over previous
//
#include <hip/hip_runtime.h>
#include <hip/hip_bf16.h>

#define DEV __device__ __forceinline__

typedef __attribute__((ext_vector_type(8))) short short8;
typedef __attribute__((ext_vector_type(4))) float f32x4;
typedef __attribute__((ext_vector_type(16))) float f32x16;
typedef __attribute__((ext_vector_type(2))) unsigned int u32x2;
typedef __attribute__((ext_vector_type(4))) unsigned int u32x4;
typedef unsigned short u16;
typedef unsigned int u32;

// B=4, T=2048, D=1024, H=16, E=64, M = B*T = 8192

DEV u16 f2bf(float f) {
    union { __hip_bfloat16 h; u16 u; } cv;
    cv.h = __float2bfloat16(f);
    return cv.u;
}

// round-half-up pack of two f32 -> bf16x2 (finite inputs only)
DEV u32 pack_bf2(float a, float b) {
    u32 ua = __builtin_bit_cast(u32, a), ub = __builtin_bit_cast(u32, b);
    return ((ua + 0x8000u) >> 16) | ((ub + 0x8000u) & 0xFFFF0000u);
}

DEV void gload_lds16(const void* g, void* l) {
    __builtin_amdgcn_global_load_lds((const __attribute__((address_space(1))) u32*)g,
                                     (__attribute__((address_space(3))) u32*)l, 16, 0, 0);
}

// ---------- transpose fp32 -> bf16 : out[c][r] = in[r][c] per blockIdx.z slab ----------
__global__ __launch_bounds__(256) void k_transpose_f32_bf16(const float* __restrict__ in,
                                                            u16* __restrict__ out,
                                                            int R, int C) {
    __shared__ float tile[64][65];
    const int x = threadIdx.x & 63, y = threadIdx.x >> 6;
    const long slab = (long)blockIdx.z * R * C;
    const int r0 = blockIdx.x * 64, c0 = blockIdx.y * 64;
#pragma unroll
    for (int i = 0; i < 16; ++i) {
        int rr = y + 4 * i;
        tile[rr][x] = in[slab + (long)(r0 + rr) * C + (c0 + x)];
    }
    __syncthreads();
#pragma unroll
    for (int i = 0; i < 16; ++i) {
        int cc = y + 4 * i;
        out[slab + (long)(c0 + cc) * R + (r0 + x)] = f2bf(tile[x][cc]);
    }
}

// ---------- transpose bf16 -> bf16 ----------
__global__ __launch_bounds__(256) void k_transpose_bf16(const u16* __restrict__ in,
                                                        u16* __restrict__ out,
                                                        int R, int C) {
    __shared__ u16 tile[64][65];
    const int x = threadIdx.x & 63, y = threadIdx.x >> 6;
    const long slab = (long)blockIdx.z * R * C;
    const int r0 = blockIdx.x * 64, c0 = blockIdx.y * 64;
#pragma unroll
    for (int i = 0; i < 16; ++i) {
        int rr = y + 4 * i;
        tile[rr][x] = in[slab + (long)(r0 + rr) * C + (c0 + x)];
    }
    __syncthreads();
#pragma unroll
    for (int i = 0; i < 16; ++i) {
        int cc = y + 4 * i;
        out[slab + (long)(c0 + cc) * R + (r0 + x)] = tile[x][cc];
    }
}

// ---------- GEMM bodies: M=8192, N=1024, K=1024, BM=BN=128, BK=32 ----------
// MODE 0 body: A = fp32 [8192][1024] (cast bf16 in staging); C -> bf16 [b][h][t][e]
DEV void gemm_m0_body(const float* __restrict__ Af, const u16* __restrict__ Bt,
                      u16* __restrict__ Cb, u16* As, u16* Bs) {
    const int tid = threadIdx.x;
    const int lane = tid & 63, wave = tid >> 6;
    const int l15 = lane & 15, l4 = lane >> 4;
    const int wr = wave >> 1, wc = wave & 1;
    const int brow = blockIdx.x * 128, bcol = blockIdx.y * 128;

    f32x4 acc[4][4] = {};

    for (int k0 = 0; k0 < 1024; k0 += 32) {
        __syncthreads();
#pragma unroll
        for (int cc = 0; cc < 2; ++cc) {
            const int c = tid + cc * 256;
            const u16* src = Bt + (long)(bcol + (c >> 2)) * 1024 + k0 + (c & 3) * 8;
            gload_lds16(src, &Bs[cc * 2048 + wave * 512]);
        }
#pragma unroll
        for (int cc = 0; cc < 2; ++cc) {
            const int c = tid + cc * 256;
            const float* src = Af + (long)(brow + (c >> 2)) * 1024 + k0 + (c & 3) * 8;
            float4 v0 = *(const float4*)src;
            float4 v1 = *(const float4*)(src + 4);
            short8 pk;
            pk[0] = (short)f2bf(v0.x); pk[1] = (short)f2bf(v0.y);
            pk[2] = (short)f2bf(v0.z); pk[3] = (short)f2bf(v0.w);
            pk[4] = (short)f2bf(v1.x); pk[5] = (short)f2bf(v1.y);
            pk[6] = (short)f2bf(v1.z); pk[7] = (short)f2bf(v1.w);
            *(short8*)&As[c * 8] = pk;
        }
        __syncthreads();

        short8 af[4], bfr[4];
#pragma unroll
        for (int m = 0; m < 4; ++m)
            af[m] = *(const short8*)&As[(wr * 64 + m * 16 + l15) * 32 + l4 * 8];
#pragma unroll
        for (int n = 0; n < 4; ++n)
            bfr[n] = *(const short8*)&Bs[(wc * 64 + n * 16 + l15) * 32 + l4 * 8];
#pragma unroll
        for (int m = 0; m < 4; ++m)
#pragma unroll
            for (int n = 0; n < 4; ++n)
                acc[m][n] = __builtin_amdgcn_mfma_f32_16x16x32_bf16(af[m], bfr[n], acc[m][n], 0, 0, 0);
    }

#pragma unroll
    for (int m = 0; m < 4; ++m)
#pragma unroll
        for (int n = 0; n < 4; ++n)
#pragma unroll
            for (int r = 0; r < 4; ++r) {
                const int g = brow + wr * 64 + m * 16 + l4 * 4 + r;
                const int ng = bcol + wc * 64 + n * 16 + l15;
                const int b = g >> 11, t = g & 2047;
                const int h = ng >> 6, e = ng & 63;
                Cb[(long)(b * 16 + h) * 131072 + (long)t * 64 + e] = f2bf(acc[m][n][r]);
            }
}

// merged Q/K/V projection (z selects input/output)
__global__ __launch_bounds__(256) void k_gemm3(const float* __restrict__ A0, const float* __restrict__ A1,
                                               const float* __restrict__ A2,
                                               const u16* __restrict__ B0, const u16* __restrict__ B1,
                                               const u16* __restrict__ B2,
                                               u16* __restrict__ C0, u16* __restrict__ C1,
                                               u16* __restrict__ C2) {
    __shared__ u16 As[128 * 32];
    __shared__ u16 Bs[128 * 32];
    const int z = blockIdx.z;
    const float* A = z == 0 ? A0 : (z == 1 ? A1 : A2);
    const u16*   Bt = z == 0 ? B0 : (z == 1 ? B1 : B2);
    u16*         C = z == 0 ? C0 : (z == 1 ? C1 : C2);
    gemm_m0_body(A, Bt, C, As, Bs);
}

// output projection: A = bf16 attn [b][h][t][e] gathered; C -> fp32 [8192][1024]
__global__ __launch_bounds__(256) void k_gemm_out(const u16* __restrict__ Ab,
                                                  const u16* __restrict__ Bt,
                                                  float* __restrict__ Cf) {
    __shared__ u16 As[128 * 32];
    __shared__ u16 Bs[128 * 32];
    const int tid = threadIdx.x;
    const int lane = tid & 63, wave = tid >> 6;
    const int l15 = lane & 15, l4 = lane >> 4;
    const int wr = wave >> 1, wc = wave & 1;
    const int brow = blockIdx.x * 128, bcol = blockIdx.y * 128;

    f32x4 acc[4][4] = {};

    for (int k0 = 0; k0 < 1024; k0 += 32) {
        __syncthreads();
#pragma unroll
        for (int cc = 0; cc < 2; ++cc) {
            const int c = tid + cc * 256;
            const u16* src = Bt + (long)(bcol + (c >> 2)) * 1024 + k0 + (c & 3) * 8;
            gload_lds16(src, &Bs[cc * 2048 + wave * 512]);
        }
        const int h = k0 >> 6, ek = k0 & 63;
#pragma unroll
        for (int cc = 0; cc < 2; ++cc) {
            const int c = tid + cc * 256;
            const int g = brow + (c >> 2);
            const int b = g >> 11, t = g & 2047;
            const u16* src = Ab + (long)(b * 16 + h) * 131072 + (long)t * 64 + ek + (c & 3) * 8;
            gload_lds16(src, &As[cc * 2048 + wave * 512]);
        }
        __syncthreads();

        short8 af[4], bfr[4];
#pragma unroll
        for (int m = 0; m < 4; ++m)
            af[m] = *(const short8*)&As[(wr * 64 + m * 16 + l15) * 32 + l4 * 8];
#pragma unroll
        for (int n = 0; n < 4; ++n)
            bfr[n] = *(const short8*)&Bs[(wc * 64 + n * 16 + l15) * 32 + l4 * 8];
#pragma unroll
        for (int m = 0; m < 4; ++m)
#pragma unroll
            for (int n = 0; n < 4; ++n)
                acc[m][n] = __builtin_amdgcn_mfma_f32_16x16x32_bf16(af[m], bfr[n], acc[m][n], 0, 0, 0);
    }

#pragma unroll
    for (int m = 0; m < 4; ++m)
#pragma unroll
        for (int n = 0; n < 4; ++n)
#pragma unroll
            for (int r = 0; r < 4; ++r) {
                const int g = brow + wr * 64 + m * 16 + l4 * 4 + r;
                const int ng = bcol + wc * 64 + n * 16 + l15;
                Cf[(long)g * 1024 + ng] = acc[m][n][r];
            }
}

// ---------- flash attention v3: 32x32 MFMA, in-register softmax ----------
// grid 1024 = 64 bh * 16 qtiles (XCD-swizzled), 4 waves * 32 q rows.
// S^T = mfma32(K, Q): lane owns q = lane&31; kv = (reg&3)+8*(reg>>2)+4*(lane>>5) (+32*tile).
// P routed to PV B-frags entirely in-register via permlane32_swap (T12).
// l accumulated by ones-MFMA; T13 defer-max (THR=8 raw -> P <= e).
__global__ __launch_bounds__(256, 4) void k_flash3(const u16* __restrict__ Qh,
                                                   const u16* __restrict__ Kh,
                                                   const u16* __restrict__ VhT,
                                                   u16* __restrict__ attn) {
    __shared__ u16 Ks[2][4096];   // [kv][d], 16B chunks XOR-swizzled by row&7
    __shared__ u16 Vs[2][4096];   // [e][kv], same swizzle

    const int tid = threadIdx.x, lane = tid & 63, w = tid >> 6;
    const int l31 = lane & 31, l5 = lane >> 5;
    const int wid = blockIdx.x;
    const int swz = (wid & 7) * 128 + (wid >> 3);   // bijective: 1024 % 8 == 0
    const int bh = swz >> 4, qt = swz & 15;
    const long base = (long)bh * (2048 * 64);
    const int q = qt * 128 + w * 32 + l31;          // this lane's q row

    // Q B-frags: qf[ksd] = Q[q][d = ksd*16 + l5*8 + j]
    short8 qf[4];
    {
        const u16* qp = Qh + base + (long)q * 64 + l5 * 8;
#pragma unroll
        for (int ksd = 0; ksd < 4; ++ksd) qf[ksd] = *(const short8*)(qp + ksd * 16);
    }

    const float CEXP = 0.18033688011112042f;   // 0.125 * log2(e)
    float mr = -INFINITY;
    f32x16 oacc0 = {}, oacc1 = {}, lacc = {};

    short8 ones;
#pragma unroll
    for (int j = 0; j < 8; ++j) ones[j] = (short)0x3F80;

    // staging: chunk c -> row r=c>>3, slot (c&7); source col pre-swizzled (^ r&7)
    const int c0 = tid, c1 = tid + 256;
    const int r0 = c0 >> 3, s0 = (c0 & 7) ^ (r0 & 7);
    const int r1 = c1 >> 3, s1 = (c1 & 7) ^ (r1 & 7);

#define STAGE(buf, t) do {                                                              \
    const long kv0_ = (long)((t) * 64);                                                 \
    gload_lds16(Kh + base + (kv0_ + r0) * 64 + s0 * 8, &Ks[buf][w * 512]);              \
    gload_lds16(Kh + base + (kv0_ + r1) * 64 + s1 * 8, &Ks[buf][2048 + w * 512]);       \
    gload_lds16(VhT + base + (long)r0 * 2048 + kv0_ + s0 * 8, &Vs[buf][w * 512]);       \
    gload_lds16(VhT + base + (long)r1 * 2048 + kv0_ + s1 * 8, &Vs[buf][2048 + w * 512]); \
  } while (0)

    STAGE(0, 0);

    for (int t = 0; t < 32; ++t) {
        const int buf = t & 1;
        __syncthreads();               // staged tile t ready; WAR-safe
        if (t < 31) STAGE(buf ^ 1, t + 1);

        const u16* Kb = &Ks[buf][0];
        const u16* Vb = &Vs[buf][0];

        // ---- QK^T (swapped, 32x32): z0 = S^T[kv 0..31][q], z1 = kv 32..63
        f32x16 z0 = {}, z1 = {};
        __builtin_amdgcn_s_setprio(1);
#pragma unroll
        for (int ksd = 0; ksd < 4; ++ksd) {
            const int sw = (ksd * 2 + l5) ^ (l31 & 7);   // row&7 == l31&7 for both tiles
            short8 kf0 = *(const short8*)(Kb + l31 * 64 + sw * 8);
            z0 = __builtin_amdgcn_mfma_f32_32x32x16_bf16(kf0, qf[ksd], z0, 0, 0, 0);
            short8 kf1 = *(const short8*)(Kb + (32 + l31) * 64 + sw * 8);
            z1 = __builtin_amdgcn_mfma_f32_32x32x16_bf16(kf1, qf[ksd], z1, 0, 0, 0);
        }
        __builtin_amdgcn_s_setprio(0);

        // ---- online softmax, in-register (lane owns the full kv-column for q)
        float vm = fmaxf(z0[0], z0[1]);
#pragma unroll
        for (int i = 2; i < 16; ++i) vm = fmaxf(vm, z0[i]);
#pragma unroll
        for (int i = 0; i < 16; ++i) vm = fmaxf(vm, z1[i]);
        vm = fmaxf(vm, __shfl_xor(vm, 32, 64));
        if (!__all(vm - mr <= 8.0f)) {     // T13 defer-max (raw THR=8 -> P <= e)
            const float nm = fmaxf(mr, vm);
            const float sc = exp2f((mr - nm) * CEXP);
            mr = nm;
#pragma unroll
            for (int i = 0; i < 16; ++i) { oacc0[i] *= sc; oacc1[i] *= sc; }
            lacc[0] *= sc;
        }
        const float nmc = -mr * CEXP;

        // ---- per 32-kv tile: exp + pack + permlane-route + PV
#pragma unroll
        for (int tile = 0; tile < 2; ++tile) {
            const f32x16& zz = tile ? z1 : z0;
            u32 W[8];
#pragma unroll
            for (int mw = 0; mw < 8; ++mw) {
                const float p0 = exp2f(fmaf(zz[2 * mw], CEXP, nmc));
                const float p1 = exp2f(fmaf(zz[2 * mw + 1], CEXP, nmc));
                W[mw] = pack_bf2(p0, p1);
            }
#pragma unroll
            for (int ksw = 0; ksw < 2; ++ksw) {
                const int ks = tile * 2 + ksw;    // 16-kv chunk index within 64
                u32x2 ra = __builtin_amdgcn_permlane32_swap(W[4 * ksw + 0], W[4 * ksw + 2], false, false);
                u32x2 rb = __builtin_amdgcn_permlane32_swap(W[4 * ksw + 1], W[4 * ksw + 3], false, false);
                u32x4 pw; pw[0] = ra[0]; pw[1] = rb[0]; pw[2] = ra[1]; pw[3] = rb[1];
                const short8 pb = __builtin_bit_cast(short8, pw);
                const int sv = (ks * 2 + l5) ^ (l31 & 7);
                __builtin_amdgcn_s_setprio(1);
                short8 vf0 = *(const short8*)(Vb + l31 * 64 + sv * 8);
                oacc0 = __builtin_amdgcn_mfma_f32_32x32x16_bf16(vf0, pb, oacc0, 0, 0, 0);
                short8 vf1 = *(const short8*)(Vb + (32 + l31) * 64 + sv * 8);
                oacc1 = __builtin_amdgcn_mfma_f32_32x32x16_bf16(vf1, pb, oacc1, 0, 0, 0);
                lacc = __builtin_amdgcn_mfma_f32_32x32x16_bf16(ones, pb, lacc, 0, 0, 0);
                __builtin_amdgcn_s_setprio(0);
            }
        }
    }
#undef STAGE

    // ---- epilogue: O^T lane layout: q = l31, e = (reg&3) + 8*(reg>>2) + 4*l5
    const float inv = 1.0f / lacc[0];
    u16* op = attn + base + (long)q * 64;
#pragma unroll
    for (int et = 0; et < 2; ++et) {
        const f32x16& oa = et ? oacc1 : oacc0;
#pragma unroll
        for (int rq = 0; rq < 4; ++rq) {
            u32x2 st;
            st[0] = pack_bf2(oa[4 * rq + 0] * inv, oa[4 * rq + 1] * inv);
            st[1] = pack_bf2(oa[4 * rq + 2] * inv, oa[4 * rq + 3] * inv);
            *(u32x2*)(op + et * 32 + rq * 8 + l5 * 4) = st;
        }
    }
}

extern "C" void kernel_launch(void* const* d_in, const int* in_sizes, int n_in,
                              void* d_out, int out_size, void* d_ws, size_t ws_size,
                              hipStream_t stream) {
    (void)in_sizes; (void)n_in; (void)out_size; (void)ws_size;
    const float* Q  = (const float*)d_in[0];
    const float* K  = (const float*)d_in[1];
    const float* V  = (const float*)d_in[2];
    const float* Wq = (const float*)d_in[3];
    const float* Wk = (const float*)d_in[4];
    const float* Wv = (const float*)d_in[5];
    const float* Wo = (const float*)d_in[6];

    char* ws = (char*)d_ws;
    auto WS = [&](size_t mb) { return (u16*)(ws + (mb << 20)); };
    u16* WqT  = WS(0);    // [1024][1024] bf16 (B^T layouts)   2MB each
    u16* WkT  = WS(2);
    u16* WvT  = WS(4);
    u16* WoT  = WS(6);
    u16* Qh   = WS(8);    // [64][2048][64] bf16   16MB each
    u16* Kh   = WS(24);
    u16* Vh   = WS(40);
    u16* VhT  = WS(56);   // [64][64][2048]
    u16* attn = WS(72);   // [64][2048][64]        ends at 88MB

    dim3 b256(256);
    // weights -> B^T bf16. Wq/Wk/Wv: per head [1024d][64e] -> [64e][1024d]
    k_transpose_f32_bf16<<<dim3(16, 1, 16), b256, 0, stream>>>(Wq, WqT, 1024, 64);
    k_transpose_f32_bf16<<<dim3(16, 1, 16), b256, 0, stream>>>(Wk, WkT, 1024, 64);
    k_transpose_f32_bf16<<<dim3(16, 1, 16), b256, 0, stream>>>(Wv, WvT, 1024, 64);
    // Wo: [1024 he][1024 D] -> [1024 D][1024 he]
    k_transpose_f32_bf16<<<dim3(16, 16, 1), b256, 0, stream>>>(Wo, WoT, 1024, 1024);

    // merged Q/K/V projections
    k_gemm3<<<dim3(64, 8, 3), b256, 0, stream>>>(Q, K, V, WqT, WkT, WvT, Qh, Kh, Vh);

    // V transpose per (b,h): [2048][64] -> [64][2048]
    k_transpose_bf16<<<dim3(32, 1, 64), b256, 0, stream>>>(Vh, VhT, 2048, 64);

    // attention
    k_flash3<<<dim3(1024), b256, 0, stream>>>(Qh, Kh, VhT, attn);

    // output projection
    k_gemm_out<<<dim3(64, 8), b256, 0, stream>>>(attn, WoT, (float*)d_out);
}

// Round 4
// 227.618 us; speedup vs baseline: 2.6679x; 1.0808x over previous
//
#include <hip/hip_runtime.h>
#include <hip/hip_bf16.h>

#define DEV __device__ __forceinline__

typedef __attribute__((ext_vector_type(8))) short short8;
typedef __attribute__((ext_vector_type(4))) float f32x4;
typedef __attribute__((ext_vector_type(16))) float f32x16;
typedef __attribute__((ext_vector_type(2))) unsigned int u32x2;
typedef __attribute__((ext_vector_type(4))) unsigned int u32x4;
typedef unsigned short u16;
typedef unsigned int u32;

// B=4, T=2048, D=1024, H=16, E=64, M = B*T = 8192

DEV u16 f2bf(float f) {
    union { __hip_bfloat16 h; u16 u; } cv;
    cv.h = __float2bfloat16(f);
    return cv.u;
}

// raw HW exp2 (1 TRANS op; args here are <= ~1.45, denorm-flush on deep-negative is fine)
DEV float exp2_raw(float x) {
    float r;
    asm("v_exp_f32 %0, %1" : "=v"(r) : "v"(x));
    return r;
}

// packed f32x2 -> bf16x2, RNE (1 VALU op); src0 -> low half
DEV u32 cvtpk_bf2(float lo, float hi) {
    u32 r;
    asm("v_cvt_pk_bf16_f32 %0, %1, %2" : "=v"(r) : "v"(lo), "v"(hi));
    return r;
}

DEV float max3f(float a, float b, float c) { return fmaxf(fmaxf(a, b), c); }

DEV void gload_lds16(const void* g, void* l) {
    __builtin_amdgcn_global_load_lds((const __attribute__((address_space(1))) u32*)g,
                                     (__attribute__((address_space(3))) u32*)l, 16, 0, 0);
}

// ---------- transpose fp32 -> bf16 : out[c][r] = in[r][c] per slab ----------
// 3-way merged variant for Wq/Wk/Wv (z = which*16 + head)
__global__ __launch_bounds__(256) void k_transpose_w3(const float* __restrict__ W0,
                                                      const float* __restrict__ W1,
                                                      const float* __restrict__ W2,
                                                      u16* __restrict__ O0,
                                                      u16* __restrict__ O1,
                                                      u16* __restrict__ O2) {
    __shared__ float tile[64][65];
    const int x = threadIdx.x & 63, y = threadIdx.x >> 6;
    const int which = blockIdx.z >> 4, slab_i = blockIdx.z & 15;
    const float* in = which == 0 ? W0 : (which == 1 ? W1 : W2);
    u16* out = which == 0 ? O0 : (which == 1 ? O1 : O2);
    const long slab = (long)slab_i * 1024 * 64;
    const int r0 = blockIdx.x * 64;
#pragma unroll
    for (int i = 0; i < 16; ++i) {
        int rr = y + 4 * i;
        tile[rr][x] = in[slab + (long)(r0 + rr) * 64 + x];
    }
    __syncthreads();
#pragma unroll
    for (int i = 0; i < 16; ++i) {
        int cc = y + 4 * i;
        out[slab + (long)cc * 1024 + (r0 + x)] = f2bf(tile[x][cc]);
    }
}

__global__ __launch_bounds__(256) void k_transpose_f32_bf16(const float* __restrict__ in,
                                                            u16* __restrict__ out,
                                                            int R, int C) {
    __shared__ float tile[64][65];
    const int x = threadIdx.x & 63, y = threadIdx.x >> 6;
    const long slab = (long)blockIdx.z * R * C;
    const int r0 = blockIdx.x * 64, c0 = blockIdx.y * 64;
#pragma unroll
    for (int i = 0; i < 16; ++i) {
        int rr = y + 4 * i;
        tile[rr][x] = in[slab + (long)(r0 + rr) * C + (c0 + x)];
    }
    __syncthreads();
#pragma unroll
    for (int i = 0; i < 16; ++i) {
        int cc = y + 4 * i;
        out[slab + (long)(c0 + cc) * R + (r0 + x)] = f2bf(tile[x][cc]);
    }
}

// ---------- transpose bf16 -> bf16 ----------
__global__ __launch_bounds__(256) void k_transpose_bf16(const u16* __restrict__ in,
                                                        u16* __restrict__ out,
                                                        int R, int C) {
    __shared__ u16 tile[64][65];
    const int x = threadIdx.x & 63, y = threadIdx.x >> 6;
    const long slab = (long)blockIdx.z * R * C;
    const int r0 = blockIdx.x * 64, c0 = blockIdx.y * 64;
#pragma unroll
    for (int i = 0; i < 16; ++i) {
        int rr = y + 4 * i;
        tile[rr][x] = in[slab + (long)(r0 + rr) * C + (c0 + x)];
    }
    __syncthreads();
#pragma unroll
    for (int i = 0; i < 16; ++i) {
        int cc = y + 4 * i;
        out[slab + (long)(c0 + cc) * R + (r0 + x)] = tile[x][cc];
    }
}

// ---------- GEMM bodies: M=8192, N=1024, K=1024, BM=BN=128, BK=32 ----------
DEV void gemm_m0_body(const float* __restrict__ Af, const u16* __restrict__ Bt,
                      u16* __restrict__ Cb, u16* As, u16* Bs) {
    const int tid = threadIdx.x;
    const int lane = tid & 63, wave = tid >> 6;
    const int l15 = lane & 15, l4 = lane >> 4;
    const int wr = wave >> 1, wc = wave & 1;
    const int brow = blockIdx.x * 128, bcol = blockIdx.y * 128;

    f32x4 acc[4][4] = {};

    for (int k0 = 0; k0 < 1024; k0 += 32) {
        __syncthreads();
#pragma unroll
        for (int cc = 0; cc < 2; ++cc) {
            const int c = tid + cc * 256;
            const u16* src = Bt + (long)(bcol + (c >> 2)) * 1024 + k0 + (c & 3) * 8;
            gload_lds16(src, &Bs[cc * 2048 + wave * 512]);
        }
#pragma unroll
        for (int cc = 0; cc < 2; ++cc) {
            const int c = tid + cc * 256;
            const float* src = Af + (long)(brow + (c >> 2)) * 1024 + k0 + (c & 3) * 8;
            float4 v0 = *(const float4*)src;
            float4 v1 = *(const float4*)(src + 4);
            short8 pk;
            pk[0] = (short)f2bf(v0.x); pk[1] = (short)f2bf(v0.y);
            pk[2] = (short)f2bf(v0.z); pk[3] = (short)f2bf(v0.w);
            pk[4] = (short)f2bf(v1.x); pk[5] = (short)f2bf(v1.y);
            pk[6] = (short)f2bf(v1.z); pk[7] = (short)f2bf(v1.w);
            *(short8*)&As[c * 8] = pk;
        }
        __syncthreads();

        short8 af[4], bfr[4];
#pragma unroll
        for (int m = 0; m < 4; ++m)
            af[m] = *(const short8*)&As[(wr * 64 + m * 16 + l15) * 32 + l4 * 8];
#pragma unroll
        for (int n = 0; n < 4; ++n)
            bfr[n] = *(const short8*)&Bs[(wc * 64 + n * 16 + l15) * 32 + l4 * 8];
#pragma unroll
        for (int m = 0; m < 4; ++m)
#pragma unroll
            for (int n = 0; n < 4; ++n)
                acc[m][n] = __builtin_amdgcn_mfma_f32_16x16x32_bf16(af[m], bfr[n], acc[m][n], 0, 0, 0);
    }

#pragma unroll
    for (int m = 0; m < 4; ++m)
#pragma unroll
        for (int n = 0; n < 4; ++n)
#pragma unroll
            for (int r = 0; r < 4; ++r) {
                const int g = brow + wr * 64 + m * 16 + l4 * 4 + r;
                const int ng = bcol + wc * 64 + n * 16 + l15;
                const int b = g >> 11, t = g & 2047;
                const int h = ng >> 6, e = ng & 63;
                Cb[(long)(b * 16 + h) * 131072 + (long)t * 64 + e] = f2bf(acc[m][n][r]);
            }
}

__global__ __launch_bounds__(256) void k_gemm3(const float* __restrict__ A0, const float* __restrict__ A1,
                                               const float* __restrict__ A2,
                                               const u16* __restrict__ B0, const u16* __restrict__ B1,
                                               const u16* __restrict__ B2,
                                               u16* __restrict__ C0, u16* __restrict__ C1,
                                               u16* __restrict__ C2) {
    __shared__ u16 As[128 * 32];
    __shared__ u16 Bs[128 * 32];
    const int z = blockIdx.z;
    const float* A = z == 0 ? A0 : (z == 1 ? A1 : A2);
    const u16*   Bt = z == 0 ? B0 : (z == 1 ? B1 : B2);
    u16*         C = z == 0 ? C0 : (z == 1 ? C1 : C2);
    gemm_m0_body(A, Bt, C, As, Bs);
}

__global__ __launch_bounds__(256) void k_gemm_out(const u16* __restrict__ Ab,
                                                  const u16* __restrict__ Bt,
                                                  float* __restrict__ Cf) {
    __shared__ u16 As[128 * 32];
    __shared__ u16 Bs[128 * 32];
    const int tid = threadIdx.x;
    const int lane = tid & 63, wave = tid >> 6;
    const int l15 = lane & 15, l4 = lane >> 4;
    const int wr = wave >> 1, wc = wave & 1;
    const int brow = blockIdx.x * 128, bcol = blockIdx.y * 128;

    f32x4 acc[4][4] = {};

    for (int k0 = 0; k0 < 1024; k0 += 32) {
        __syncthreads();
#pragma unroll
        for (int cc = 0; cc < 2; ++cc) {
            const int c = tid + cc * 256;
            const u16* src = Bt + (long)(bcol + (c >> 2)) * 1024 + k0 + (c & 3) * 8;
            gload_lds16(src, &Bs[cc * 2048 + wave * 512]);
        }
        const int h = k0 >> 6, ek = k0 & 63;
#pragma unroll
        for (int cc = 0; cc < 2; ++cc) {
            const int c = tid + cc * 256;
            const int g = brow + (c >> 2);
            const int b = g >> 11, t = g & 2047;
            const u16* src = Ab + (long)(b * 16 + h) * 131072 + (long)t * 64 + ek + (c & 3) * 8;
            gload_lds16(src, &As[cc * 2048 + wave * 512]);
        }
        __syncthreads();

        short8 af[4], bfr[4];
#pragma unroll
        for (int m = 0; m < 4; ++m)
            af[m] = *(const short8*)&As[(wr * 64 + m * 16 + l15) * 32 + l4 * 8];
#pragma unroll
        for (int n = 0; n < 4; ++n)
            bfr[n] = *(const short8*)&Bs[(wc * 64 + n * 16 + l15) * 32 + l4 * 8];
#pragma unroll
        for (int m = 0; m < 4; ++m)
#pragma unroll
            for (int n = 0; n < 4; ++n)
                acc[m][n] = __builtin_amdgcn_mfma_f32_16x16x32_bf16(af[m], bfr[n], acc[m][n], 0, 0, 0);
    }

#pragma unroll
    for (int m = 0; m < 4; ++m)
#pragma unroll
        for (int n = 0; n < 4; ++n)
#pragma unroll
            for (int r = 0; r < 4; ++r) {
                const int g = brow + wr * 64 + m * 16 + l4 * 4 + r;
                const int ng = bcol + wc * 64 + n * 16 + l15;
                Cf[(long)g * 1024 + ng] = acc[m][n][r];
            }
}

// ---------- flash attention v4: 32x32 MFMA, in-register softmax, lean VALU ----------
__global__ __launch_bounds__(256, 4) void k_flash4(const u16* __restrict__ Qh,
                                                   const u16* __restrict__ Kh,
                                                   const u16* __restrict__ VhT,
                                                   u16* __restrict__ attn) {
    __shared__ u16 Ks[2][4096];   // [kv][d], 16B chunks XOR-swizzled by row&7
    __shared__ u16 Vs[2][4096];   // [e][kv], same swizzle

    const int tid = threadIdx.x, lane = tid & 63, w = tid >> 6;
    const int l31 = lane & 31, l5 = lane >> 5;
    const int wid = blockIdx.x;
    const int swz = (wid & 7) * 128 + (wid >> 3);   // bijective: 1024 % 8 == 0
    const int bh = swz >> 4, qt = swz & 15;
    const long base = (long)bh * (2048 * 64);
    const int q = qt * 128 + w * 32 + l31;          // this lane's q row

    // Q B-frags: qf[ksd] = Q[q][d = ksd*16 + l5*8 + j]
    short8 qf[4];
    {
        const u16* qp = Qh + base + (long)q * 64 + l5 * 8;
#pragma unroll
        for (int ksd = 0; ksd < 4; ++ksd) qf[ksd] = *(const short8*)(qp + ksd * 16);
    }

    // hoisted LDS byte offsets (shared by K and V reads: same swizzle formula)
    int off[4];
#pragma unroll
    for (int ksd = 0; ksd < 4; ++ksd)
        off[ksd] = l31 * 128 + (((ksd * 2 + l5) ^ (l31 & 7)) << 4);

    const float CEXP = 0.18033688011112042f;   // 0.125 * log2(e)
    float mr = -INFINITY;
    f32x16 oacc0 = {}, oacc1 = {}, lacc = {};

    short8 ones;
#pragma unroll
    for (int j = 0; j < 8; ++j) ones[j] = (short)0x3F80;

    // staging: chunk c -> row r=c>>3, slot (c&7)^(r&7) pre-swizzled at the source
    const int c0 = tid, c1 = tid + 256;
    const int r0 = c0 >> 3, s0 = (c0 & 7) ^ (r0 & 7);
    const int r1 = c1 >> 3, s1 = (c1 & 7) ^ (r1 & 7);

#define STAGE(buf, t) do {                                                              \
    const long kv0_ = (long)((t) * 64);                                                 \
    gload_lds16(Kh + base + (kv0_ + r0) * 64 + s0 * 8, &Ks[buf][w * 512]);              \
    gload_lds16(Kh + base + (kv0_ + r1) * 64 + s1 * 8, &Ks[buf][2048 + w * 512]);       \
    gload_lds16(VhT + base + (long)r0 * 2048 + kv0_ + s0 * 8, &Vs[buf][w * 512]);       \
    gload_lds16(VhT + base + (long)r1 * 2048 + kv0_ + s1 * 8, &Vs[buf][2048 + w * 512]); \
  } while (0)

    STAGE(0, 0);

#pragma unroll 2
    for (int t = 0; t < 32; ++t) {
        const int buf = t & 1;
        __syncthreads();               // staged tile t ready; WAR-safe
        if (t < 31) STAGE(buf ^ 1, t + 1);

        const char* Kb = (const char*)&Ks[buf][0];
        const char* Vb = (const char*)&Vs[buf][0];

        // ---- QK^T (swapped, 32x32): z0 = S^T[kv 0..31][q], z1 = kv 32..63
        f32x16 z0 = {}, z1 = {};
#pragma unroll
        for (int ksd = 0; ksd < 4; ++ksd) {
            short8 kf0 = *(const short8*)(Kb + off[ksd]);
            z0 = __builtin_amdgcn_mfma_f32_32x32x16_bf16(kf0, qf[ksd], z0, 0, 0, 0);
            short8 kf1 = *(const short8*)(Kb + 4096 + off[ksd]);
            z1 = __builtin_amdgcn_mfma_f32_32x32x16_bf16(kf1, qf[ksd], z1, 0, 0, 0);
        }

        // ---- row max via max3 tree (shallow), then cross-half via permlane
        float a0 = max3f(z0[0],  z0[1],  z0[2]);
        float a1 = max3f(z0[3],  z0[4],  z0[5]);
        float a2 = max3f(z0[6],  z0[7],  z0[8]);
        float a3 = max3f(z0[9],  z0[10], z0[11]);
        float a4 = max3f(z0[12], z0[13], z0[14]);
        float a5 = max3f(z0[15], z1[0],  z1[1]);
        float a6 = max3f(z1[2],  z1[3],  z1[4]);
        float a7 = max3f(z1[5],  z1[6],  z1[7]);
        float a8 = max3f(z1[8],  z1[9],  z1[10]);
        float a9 = max3f(z1[11], z1[12], z1[13]);
        float aa = fmaxf(z1[14], z1[15]);
        float b0 = max3f(a0, a1, a2);
        float b1 = max3f(a3, a4, a5);
        float b2 = max3f(a6, a7, a8);
        float b3 = fmaxf(a9, aa);
        float vm = fmaxf(max3f(b0, b1, b2), b3);
        {
            u32x2 pp = __builtin_amdgcn_permlane32_swap(__builtin_bit_cast(u32, vm),
                                                        __builtin_bit_cast(u32, vm), false, false);
            vm = fmaxf(__builtin_bit_cast(float, pp[0]), __builtin_bit_cast(float, pp[1]));
        }
        if (!__all(vm - mr <= 8.0f)) {     // T13 defer-max (raw THR=8 -> P <= e)
            const float nm = fmaxf(mr, vm);
            const float sc = exp2_raw((mr - nm) * CEXP);
            mr = nm;
#pragma unroll
            for (int i = 0; i < 16; ++i) { oacc0[i] *= sc; oacc1[i] *= sc; }
            lacc[0] *= sc;
        }
        const float nmc = -mr * CEXP;

        // ---- per 32-kv tile: exp + pack + permlane-route + PV
#pragma unroll
        for (int tile = 0; tile < 2; ++tile) {
            const f32x16& zz = tile ? z1 : z0;
            u32 W[8];
#pragma unroll
            for (int mw = 0; mw < 8; ++mw) {
                const float p0 = exp2_raw(fmaf(zz[2 * mw],     CEXP, nmc));
                const float p1 = exp2_raw(fmaf(zz[2 * mw + 1], CEXP, nmc));
                W[mw] = cvtpk_bf2(p0, p1);
            }
#pragma unroll
            for (int ksw = 0; ksw < 2; ++ksw) {
                const int ks = tile * 2 + ksw;    // 16-kv chunk index within 64
                u32x2 ra = __builtin_amdgcn_permlane32_swap(W[4 * ksw + 0], W[4 * ksw + 2], false, false);
                u32x2 rb = __builtin_amdgcn_permlane32_swap(W[4 * ksw + 1], W[4 * ksw + 3], false, false);
                u32x4 pw; pw[0] = ra[0]; pw[1] = rb[0]; pw[2] = ra[1]; pw[3] = rb[1];
                const short8 pb = __builtin_bit_cast(short8, pw);
                short8 vf0 = *(const short8*)(Vb + off[ks]);
                oacc0 = __builtin_amdgcn_mfma_f32_32x32x16_bf16(vf0, pb, oacc0, 0, 0, 0);
                short8 vf1 = *(const short8*)(Vb + 4096 + off[ks]);
                oacc1 = __builtin_amdgcn_mfma_f32_32x32x16_bf16(vf1, pb, oacc1, 0, 0, 0);
                lacc = __builtin_amdgcn_mfma_f32_32x32x16_bf16(ones, pb, lacc, 0, 0, 0);
            }
        }
    }
#undef STAGE

    // ---- epilogue: O^T lane layout: q = l31, e = (reg&3) + 8*(reg>>2) + 4*l5
    const float inv = 1.0f / lacc[0];
    u16* op = attn + base + (long)q * 64;
#pragma unroll
    for (int et = 0; et < 2; ++et) {
        const f32x16& oa = et ? oacc1 : oacc0;
#pragma unroll
        for (int rq = 0; rq < 4; ++rq) {
            u32x2 st;
            st[0] = cvtpk_bf2(oa[4 * rq + 0] * inv, oa[4 * rq + 1] * inv);
            st[1] = cvtpk_bf2(oa[4 * rq + 2] * inv, oa[4 * rq + 3] * inv);
            *(u32x2*)(op + et * 32 + rq * 8 + l5 * 4) = st;
        }
    }
}

extern "C" void kernel_launch(void* const* d_in, const int* in_sizes, int n_in,
                              void* d_out, int out_size, void* d_ws, size_t ws_size,
                              hipStream_t stream) {
    (void)in_sizes; (void)n_in; (void)out_size; (void)ws_size;
    const float* Q  = (const float*)d_in[0];
    const float* K  = (const float*)d_in[1];
    const float* V  = (const float*)d_in[2];
    const float* Wq = (const float*)d_in[3];
    const float* Wk = (const float*)d_in[4];
    const float* Wv = (const float*)d_in[5];
    const float* Wo = (const float*)d_in[6];

    char* ws = (char*)d_ws;
    auto WS = [&](size_t mb) { return (u16*)(ws + (mb << 20)); };
    u16* WqT  = WS(0);    // [1024][1024] bf16 (B^T layouts)   2MB each
    u16* WkT  = WS(2);
    u16* WvT  = WS(4);
    u16* WoT  = WS(6);
    u16* Qh   = WS(8);    // [64][2048][64] bf16   16MB each
    u16* Kh   = WS(24);
    u16* Vh   = WS(40);
    u16* VhT  = WS(56);   // [64][64][2048]
    u16* attn = WS(72);   // [64][2048][64]        ends at 88MB

    dim3 b256(256);
    // weights -> B^T bf16. Wq/Wk/Wv merged: per head [1024d][64e] -> [64e][1024d]
    k_transpose_w3<<<dim3(16, 1, 48), b256, 0, stream>>>(Wq, Wk, Wv, WqT, WkT, WvT);
    // Wo: [1024 he][1024 D] -> [1024 D][1024 he]
    k_transpose_f32_bf16<<<dim3(16, 16, 1), b256, 0, stream>>>(Wo, WoT, 1024, 1024);

    // merged Q/K/V projections
    k_gemm3<<<dim3(64, 8, 3), b256, 0, stream>>>(Q, K, V, WqT, WkT, WvT, Qh, Kh, Vh);

    // V transpose per (b,h): [2048][64] -> [64][2048]
    k_transpose_bf16<<<dim3(32, 1, 64), b256, 0, stream>>>(Vh, VhT, 2048, 64);

    // attention
    k_flash4<<<dim3(1024), b256, 0, stream>>>(Qh, Kh, VhT, attn);

    // output projection
    k_gemm_out<<<dim3(64, 8), b256, 0, stream>>>(attn, WoT, (float*)d_out);
}